// Round 7
// baseline (905.198 us; speedup 1.0000x reference)
//
#include <hip/hip_runtime.h>
#include <hip/hip_bf16.h>

typedef __bf16 bf16_t;
typedef __bf16 bf16x8 __attribute__((ext_vector_type(8)));
typedef float  f32x4  __attribute__((ext_vector_type(4)));

constexpr int T_ = 2048, H_ = 2048, I_ = 5632, E_ = 8, S_ = T_ * 2;

// ---- workspace layout (bytes) ----  total ~88.2 MB
constexpr size_t OFF_HB    = 0;                                   // bf16 hidden  [T][H]
constexpr size_t OFF_HOUT  = OFF_HB    + (size_t)T_ * H_ * 2;     // bf16 h       [S][I]
constexpr size_t OFF_DPART = OFF_HOUT  + (size_t)S_ * I_ * 2;     // f32 downpart [S][H]
constexpr size_t OFF_TOS   = OFF_DPART + (size_t)S_ * H_ * 4;     // int token_of_slot[S]
constexpr size_t OFF_SOT   = OFF_TOS   + (size_t)S_ * 4;          // int slot_of_tk[T*2]
constexpr size_t OFF_TKI   = OFF_SOT   + (size_t)S_ * 4;          // int topk_idx[T*2]
constexpr size_t OFF_TKW   = OFF_TKI   + (size_t)S_ * 4;          // f32 topk_w[T*2]
constexpr size_t OFF_CNT   = OFF_TKW   + (size_t)S_ * 4;          // int counts[E]
constexpr size_t OFF_OFFS  = OFF_CNT   + 64;                      // int offs[E]
constexpr size_t OFF_CUR   = OFF_OFFS  + 64;                      // int cursor[E]

// async global->LDS, 16B per lane. LDS dest = wave-uniform base + lane*16 (HW).
__device__ __forceinline__ void gload16(const void* g, void* l) {
  __builtin_amdgcn_global_load_lds(
      (const __attribute__((address_space(1))) void*)g,
      (__attribute__((address_space(3))) void*)l, 16, 0, 0);
}

__device__ __forceinline__ bf16x8 cvt8(f32x4 a, f32x4 b) {
  bf16x8 r;
  r[0]=(bf16_t)a[0]; r[1]=(bf16_t)a[1]; r[2]=(bf16_t)a[2]; r[3]=(bf16_t)a[3];
  r[4]=(bf16_t)b[0]; r[5]=(bf16_t)b[1]; r[6]=(bf16_t)b[2]; r[7]=(bf16_t)b[3];
  return r;
}

// ================= router: logits, softmax, top-2, bf16 convert =================
__global__ __launch_bounds__(256)
void router_kernel(const float* __restrict__ hs, const float* __restrict__ gw,
                   int* __restrict__ tki, float* __restrict__ tkw,
                   int* __restrict__ counts, bf16_t* __restrict__ hb)
{
  const int t = blockIdx.x;
  const int tid = threadIdx.x;
  const int lane = tid & 63, wid = tid >> 6;
  const float* hrow = hs + (size_t)t * H_;
  const int c0 = tid * 8;
  float4 h0 = *(const float4*)(hrow + c0);
  float4 h1 = *(const float4*)(hrow + c0 + 4);
  bf16x8 hv;
  hv[0]=(bf16_t)h0.x; hv[1]=(bf16_t)h0.y; hv[2]=(bf16_t)h0.z; hv[3]=(bf16_t)h0.w;
  hv[4]=(bf16_t)h1.x; hv[5]=(bf16_t)h1.y; hv[6]=(bf16_t)h1.z; hv[7]=(bf16_t)h1.w;
  *(bf16x8*)(hb + (size_t)t * H_ + c0) = hv;

  float acc[E_];
  #pragma unroll
  for (int e = 0; e < E_; ++e) {
    const float* g = gw + (size_t)e * H_ + c0;
    float4 g0 = *(const float4*)(g);
    float4 g1 = *(const float4*)(g + 4);
    acc[e] = h0.x*g0.x + h0.y*g0.y + h0.z*g0.z + h0.w*g0.w
           + h1.x*g1.x + h1.y*g1.y + h1.z*g1.z + h1.w*g1.w;
  }
  #pragma unroll
  for (int e = 0; e < E_; ++e)
    #pragma unroll
    for (int o = 32; o > 0; o >>= 1)
      acc[e] += __shfl_down(acc[e], o);
  __shared__ float red[4][E_];
  if (lane == 0)
    #pragma unroll
    for (int e = 0; e < E_; ++e) red[wid][e] = acc[e];
  __syncthreads();
  if (tid == 0) {
    float l[E_];
    #pragma unroll
    for (int e = 0; e < E_; ++e) l[e] = red[0][e] + red[1][e] + red[2][e] + red[3][e];
    float m = l[0];
    #pragma unroll
    for (int e = 1; e < E_; ++e) m = fmaxf(m, l[e]);
    float p[E_]; float s = 0.f;
    #pragma unroll
    for (int e = 0; e < E_; ++e) { p[e] = __expf(l[e] - m); s += p[e]; }
    int i1 = 0;
    #pragma unroll
    for (int e = 1; e < E_; ++e) if (l[e] > l[i1]) i1 = e;
    int i2 = (i1 == 0) ? 1 : 0;
    #pragma unroll
    for (int e = 0; e < E_; ++e) if (e != i1 && l[e] > l[i2]) i2 = e;
    tki[2*t] = i1; tki[2*t+1] = i2;
    tkw[2*t] = p[i1] / s; tkw[2*t+1] = p[i2] / s;
    atomicAdd(&counts[i1], 1);
    atomicAdd(&counts[i2], 1);
  }
}

// ================= scan: expert offsets + slot lists =================
__global__ void scan_kernel(const int* __restrict__ counts, const int* __restrict__ tki,
                            int* __restrict__ offs, int* __restrict__ cursor,
                            int* __restrict__ tos, int* __restrict__ sot)
{
  if (threadIdx.x == 0) {
    int run = 0;
    for (int e = 0; e < E_; ++e) { offs[e] = run; cursor[e] = run; run += counts[e]; }
  }
  __syncthreads();
  for (int t = threadIdx.x; t < T_; t += blockDim.x) {
    #pragma unroll
    for (int k = 0; k < 2; ++k) {
      int e = tki[2*t + k];
      int s = atomicAdd(&cursor[e], 1);
      tos[s] = t;
      sot[2*t + k] = s;
    }
  }
}

// ================= GEMM1: gathered hidden x w1^T, dual (gate,up), fused silu*mul =================
// T3-minimum 2-phase (m97/m230-V0 shape): { stage(next); compute(cur); __syncthreads(); }.
// One barrier/K-step, drain after compute, 3 blocks/CU (48 KB LDS) provide antiphase TLP.
// All staging via global_load_lds. Zero-conflict LDS layout (r5-proven): 128B rows,
// 8x16B slots, physical slot = wanted ^ (row&7), realized via pre-swizzled global sources.
// A (bf16, 32 cols = 64B/row) is PAIR-PACKED: LDS row' = token-row>>1 holds both rows
// (wanted slot w: w>>2 = row&1, w&3 = 16B k-slot).
constexpr int G1_BM = 128, G1_BN = 64, G1_BK = 32;
constexpr int G1_BUF = 8192 + 16384;   // A 8KB + B(f32,128 rows: 64 gate + 64 up) 16KB

__global__ __launch_bounds__(256, 3)
void gemm1_kernel(const bf16_t* __restrict__ hb, const float* __restrict__ w1,
                  const int* __restrict__ tos, const int* __restrict__ offs,
                  const int* __restrict__ counts, bf16_t* __restrict__ hout)
{
  // XCD-chunked raster: expert e pinned to XCD (bid&7); m-tiles innermost for L2 strip reuse.
  const int bid = blockIdx.x;
  const int e   = bid & 7;
  const int idx = bid >> 3;          // 16 m-tiles x 88 n-tiles
  const int mt  = idx & 15;
  const int nt  = idx >> 4;

  const int cnt = counts[e];
  const int m0 = mt * G1_BM;
  if (m0 >= cnt) return;
  const int off = offs[e];
  const int n0 = nt * G1_BN;

  const float* Wg = w1 + (size_t)e * (2 * (size_t)I_ * H_) + (size_t)n0 * H_;

  __shared__ char smem[2 * G1_BUF];   // 48KB -> 3 blocks/CU

  const int tid = threadIdx.x;
  const int lane = tid & 63, wid = tid >> 6;
  const int wm = wid >> 1, wn = wid & 1;
  const int l15 = lane & 15, l4 = lane >> 4;

  // --- A staging: 8 chunks of 1KB (8 row-pairs x 128B); wave stages chunks wid*2+{0,1}.
  // lane -> row' = q*8+(lane>>3), phys = lane&7, wanted w = phys ^ (row'&7);
  // token row = 2*row' + (w>>2), k 16B-slot = w&3.
  const bf16_t* agp[2]; int aoff[2];
  #pragma unroll
  for (int i = 0; i < 2; ++i) {
    int q = wid * 2 + i;
    int rp = q * 8 + (lane >> 3);
    int w  = (lane & 7) ^ (rp & 7);
    int row = 2 * rp + (w >> 2);
    int slot = off + m0 + row, mx = off + cnt - 1;
    if (slot > mx) slot = mx;            // clamp pad rows (masked at store)
    agp[i]  = hb + (size_t)tos[slot] * H_ + (w & 3) * 8;
    aoff[i] = q * 1024;
  }
  // --- B staging (f32): 16 chunks of 1KB (8 rows x 128B); wave stages chunks wid*4+{0..3}.
  // LDS rows 0-63 = gate, 64-127 = up. lane -> row = q*8+(lane>>3), phys = lane&7,
  // wanted w = phys ^ (row&7) -> f32 col = w*4.
  const float* bgp[4]; int boff[4];
  #pragma unroll
  for (int i = 0; i < 4; ++i) {
    int q = wid * 4 + i;
    int row = q * 8 + (lane >> 3);
    int w   = (lane & 7) ^ (row & 7);
    size_t wr = (row < 64) ? (size_t)row : (size_t)(I_ - 64 + row);
    bgp[i]  = Wg + wr * H_ + w * 4;
    boff[i] = q * 1024;
  }

  auto stage = [&](int b, int t) {
    char* ab = smem + b * G1_BUF;
    char* bb = ab + 8192;
    const int k0 = t * G1_BK;
    #pragma unroll
    for (int i = 0; i < 2; ++i) gload16(agp[i] + k0, ab + aoff[i]);
    #pragma unroll
    for (int i = 0; i < 4; ++i) gload16(bgp[i] + k0, bb + boff[i]);
  };

  f32x4 accg[4][2], accu[4][2];
  #pragma unroll
  for (int mi = 0; mi < 4; ++mi)
    #pragma unroll
    for (int ni = 0; ni < 2; ++ni) {
      accg[mi][ni] = f32x4{0.f,0.f,0.f,0.f};
      accu[mi][ni] = f32x4{0.f,0.f,0.f,0.f};
    }

  // read-side lane constants
  const int physA = ((((l15 & 1) << 2) | l4) ^ ((l15 >> 1) & 7)) * 16;  // A slot byte
  const int aro   = (l15 >> 1);                                          // A row'-in-16
  const int pB0   = (((2 * l4) ^ (l15 & 7))) * 16;                       // B slot byte (pB1 = pB0^16)

  auto compute = [&](int b) {
    const char* ab = smem + b * G1_BUF;
    const char* bb = ab + 8192;
    bf16x8 af[4], bgf[2], buf2[2];
    #pragma unroll
    for (int mi = 0; mi < 4; ++mi) {
      int rp = wm * 32 + mi * 8 + aro;
      af[mi] = *(const bf16x8*)(ab + rp * 128 + physA);
    }
    #pragma unroll
    for (int ni = 0; ni < 2; ++ni) {
      int rg = wn * 32 + ni * 16 + l15;
      const char* rowg = bb + rg * 128;
      const char* rowu = bb + (rg + 64) * 128;   // (rg+64)&7 == rg&7
      f32x4 g0 = *(const f32x4*)(rowg + pB0);
      f32x4 g1 = *(const f32x4*)(rowg + (pB0 ^ 16));
      f32x4 u0 = *(const f32x4*)(rowu + pB0);
      f32x4 u1 = *(const f32x4*)(rowu + (pB0 ^ 16));
      bgf[ni]  = cvt8(g0, g1);
      buf2[ni] = cvt8(u0, u1);
    }
    #pragma unroll
    for (int mi = 0; mi < 4; ++mi)
      #pragma unroll
      for (int ni = 0; ni < 2; ++ni) {
        accg[mi][ni] = __builtin_amdgcn_mfma_f32_16x16x32_bf16(af[mi], bgf[ni],  accg[mi][ni], 0, 0, 0);
        accu[mi][ni] = __builtin_amdgcn_mfma_f32_16x16x32_bf16(af[mi], buf2[ni], accu[mi][ni], 0, 0, 0);
      }
  };

  constexpr int NK = H_ / G1_BK;   // 64
  stage(0, 0);
  __syncthreads();                 // prologue drain
  int cur = 0;
  for (int t = 0; t < NK; ++t) {
    if (t + 1 < NK) stage(cur ^ 1, t + 1);   // in flight across compute
    compute(cur);
    __syncthreads();               // drains vmcnt(0)+lgkm; next buf ready; reads done
    cur ^= 1;
  }

  // epilogue: silu(g)*u -> bf16 h[slot][i]   (C/D map: row=(lane>>4)*4+j, col=lane&15)
  #pragma unroll
  for (int mi = 0; mi < 4; ++mi)
    #pragma unroll
    for (int ni = 0; ni < 2; ++ni)
      #pragma unroll
      for (int j = 0; j < 4; ++j) {
        int rel = wm*64 + mi*16 + l4*4 + j;
        if (m0 + rel < cnt) {
          int col = n0 + wn*32 + ni*16 + l15;
          float g = accg[mi][ni][j];
          float u = accu[mi][ni][j];
          float hvv = (g / (1.0f + __expf(-g))) * u;
          hout[(size_t)(off + m0 + rel) * I_ + col] = (bf16_t)hvv;
        }
      }
}

// ================= GEMM2: h x w2^T -> per-slot partial (f32) =================
constexpr int G2_BM = 128, G2_BN = 128, G2_BK = 32;
constexpr int G2_BUF = 8192 + 16384;

__global__ __launch_bounds__(256, 3)
void gemm2_kernel(const bf16_t* __restrict__ hbuf, const float* __restrict__ w2,
                  const int* __restrict__ offs, const int* __restrict__ counts,
                  float* __restrict__ dpart)
{
  const int bid = blockIdx.x;
  const int e   = bid & 7;
  const int idx = bid >> 3;          // 16 m x 16 n
  const int mt  = idx & 15;
  const int nt  = idx >> 4;

  const int cnt = counts[e];
  const int m0 = mt * G2_BM;
  if (m0 >= cnt) return;
  const int off = offs[e];
  const int n0 = nt * G2_BN;
  const float* W = w2 + (size_t)e * ((size_t)H_ * I_) + (size_t)n0 * I_;

  __shared__ char smem[2 * G2_BUF];   // 48KB

  const int tid = threadIdx.x;
  const int lane = tid & 63, wid = tid >> 6;
  const int wm = wid >> 1, wn = wid & 1;
  const int l15 = lane & 15, l4 = lane >> 4;

  const bf16_t* agp[2]; int aoff[2];
  #pragma unroll
  for (int i = 0; i < 2; ++i) {
    int q = wid * 2 + i;
    int rp = q * 8 + (lane >> 3);
    int w  = (lane & 7) ^ (rp & 7);
    int row = 2 * rp + (w >> 2);
    int slot = off + m0 + row, mx = off + cnt - 1;
    if (slot > mx) slot = mx;
    agp[i]  = hbuf + (size_t)slot * I_ + (w & 3) * 8;
    aoff[i] = q * 1024;
  }
  const float* bgp[4]; int boff[4];
  #pragma unroll
  for (int i = 0; i < 4; ++i) {
    int q = wid * 4 + i;
    int row = q * 8 + (lane >> 3);
    int w   = (lane & 7) ^ (row & 7);
    bgp[i]  = W + (size_t)row * I_ + w * 4;
    boff[i] = q * 1024;
  }

  auto stage = [&](int b, int t) {
    char* ab = smem + b * G2_BUF;
    char* bb = ab + 8192;
    const int k0 = t * G2_BK;
    #pragma unroll
    for (int i = 0; i < 2; ++i) gload16(agp[i] + k0, ab + aoff[i]);
    #pragma unroll
    for (int i = 0; i < 4; ++i) gload16(bgp[i] + k0, bb + boff[i]);
  };

  f32x4 acc[4][4];
  #pragma unroll
  for (int mi = 0; mi < 4; ++mi)
    #pragma unroll
    for (int ni = 0; ni < 4; ++ni) acc[mi][ni] = f32x4{0.f,0.f,0.f,0.f};

  const int physA = ((((l15 & 1) << 2) | l4) ^ ((l15 >> 1) & 7)) * 16;
  const int aro   = (l15 >> 1);
  const int pB0   = (((2 * l4) ^ (l15 & 7))) * 16;

  auto compute = [&](int b) {
    const char* ab = smem + b * G2_BUF;
    const char* bb = ab + 8192;
    bf16x8 af[4], bf[4];
    #pragma unroll
    for (int mi = 0; mi < 4; ++mi) {
      int rp = wm * 32 + mi * 8 + aro;
      af[mi] = *(const bf16x8*)(ab + rp * 128 + physA);
    }
    #pragma unroll
    for (int ni = 0; ni < 4; ++ni) {
      int r = wn * 64 + ni * 16 + l15;
      const char* rowb = bb + r * 128;
      f32x4 b0 = *(const f32x4*)(rowb + pB0);
      f32x4 b1 = *(const f32x4*)(rowb + (pB0 ^ 16));
      bf[ni] = cvt8(b0, b1);
    }
    #pragma unroll
    for (int mi = 0; mi < 4; ++mi)
      #pragma unroll
      for (int ni = 0; ni < 4; ++ni)
        acc[mi][ni] = __builtin_amdgcn_mfma_f32_16x16x32_bf16(af[mi], bf[ni], acc[mi][ni], 0, 0, 0);
  };

  constexpr int NK = I_ / G2_BK;   // 176
  stage(0, 0);
  __syncthreads();
  int cur = 0;
  for (int t = 0; t < NK; ++t) {
    if (t + 1 < NK) stage(cur ^ 1, t + 1);
    compute(cur);
    __syncthreads();
    cur ^= 1;
  }

  #pragma unroll
  for (int mi = 0; mi < 4; ++mi)
    #pragma unroll
    for (int ni = 0; ni < 4; ++ni)
      #pragma unroll
      for (int j = 0; j < 4; ++j) {
        int rel = wm*64 + mi*16 + l4*4 + j;
        if (m0 + rel < cnt) {
          int col = n0 + wn*64 + ni*16 + l15;
          dpart[(size_t)(off + m0 + rel) * H_ + col] = acc[mi][ni][j];
        }
      }
}

// ================= combine: out[t] = w0*d[s0] + w1*d[s1] =================
__global__ __launch_bounds__(256)
void combine_kernel(const float* __restrict__ dpart, const int* __restrict__ sot,
                    const float* __restrict__ tkw, float* __restrict__ out)
{
  int idx = blockIdx.x * 256 + threadIdx.x;     // T*H/4 total
  int t = idx >> 9;                              // H/4 = 512
  int c = (idx & 511) * 4;
  float wA = tkw[2*t], wB = tkw[2*t+1];
  int sA = sot[2*t], sB = sot[2*t+1];
  float4 a = *(const float4*)(dpart + (size_t)sA * H_ + c);
  float4 b = *(const float4*)(dpart + (size_t)sB * H_ + c);
  float4 o;
  o.x = wA*a.x + wB*b.x; o.y = wA*a.y + wB*b.y;
  o.z = wA*a.z + wB*b.z; o.w = wA*a.w + wB*b.w;
  *(float4*)(out + (size_t)t * H_ + c) = o;
}

extern "C" void kernel_launch(void* const* d_in, const int* in_sizes, int n_in,
                              void* d_out, int out_size, void* d_ws, size_t ws_size,
                              hipStream_t stream) {
  const float* hs = (const float*)d_in[0];
  const float* gw = (const float*)d_in[1];
  const float* w1 = (const float*)d_in[2];
  const float* w2 = (const float*)d_in[3];
  float* out = (float*)d_out;
  char* ws = (char*)d_ws;

  bf16_t* hb    = (bf16_t*)(ws + OFF_HB);
  bf16_t* hout  = (bf16_t*)(ws + OFF_HOUT);
  float*  dpart = (float*) (ws + OFF_DPART);
  int*    tos   = (int*)   (ws + OFF_TOS);
  int*    sot   = (int*)   (ws + OFF_SOT);
  int*    tki   = (int*)   (ws + OFF_TKI);
  float*  tkw   = (float*) (ws + OFF_TKW);
  int*    cnt   = (int*)   (ws + OFF_CNT);
  int*    offp  = (int*)   (ws + OFF_OFFS);
  int*    curp  = (int*)   (ws + OFF_CUR);

  hipMemsetAsync(ws + OFF_CNT, 0, 64, stream);   // zero expert counts each call

  router_kernel<<<T_, 256, 0, stream>>>(hs, gw, tki, tkw, cnt, hb);
  scan_kernel<<<1, 256, 0, stream>>>(cnt, tki, offp, curp, tos, sot);
  gemm1_kernel<<<(T_ / G1_BM) * (I_ / G1_BN) * E_, 256, 0, stream>>>(hb, w1, tos, offp, cnt, hout);
  gemm2_kernel<<<(T_ / G2_BM) * (H_ / G2_BN) * E_, 256, 0, stream>>>(hout, w2, offp, cnt, dpart);
  combine_kernel<<<(T_ * H_ / 4) / 256, 256, 0, stream>>>(dpart, sot, tkw, out);
}